// Round 1
// baseline (56443.835 us; speedup 1.0000x reference)
//
#include <hip/hip_runtime.h>
#include <math.h>

// Problem constants (fixed by setup_inputs)
#define Bz 64
#define Tz 1024
#define Dz 512
#define Hz 256
#define Gz 1024   // 4*H
#define Kz 20

__device__ __forceinline__ float sigf(float x) { return 1.0f / (1.0f + __expf(-x)); }

// ---------------------------------------------------------------------------
// Zero-init the persistent ws region (flags + h double buffer + c state).
// 2048 ints (flags) + 65536 f (h: [parity][dir][256][64]) + 32768 f (c) = 100352 dwords
// ---------------------------------------------------------------------------
__global__ __launch_bounds__(256) void init_ws(int* p) {
    int i = blockIdx.x * 256 + threadIdx.x;
    if (i < 100352) p[i] = 0;
}

// ---------------------------------------------------------------------------
// Input-gate precompute GEMM (fp32, LDS-tiled 64x64, 4x4 microtile).
// C[dir][row][sl][b] = bias[row] + sum_k W_ih[row][k] * x[b][t(dir,sl)][k]
//   M = 1024 gate rows, N = Tc*64 (sl,b), K = 512.
// Gates layout [dir][row][sl][b] makes the recurrent kernel's reads coalesced
// (lanes = consecutive b) and this kernel's stores contiguous float4s.
// ---------------------------------------------------------------------------
__global__ __launch_bounds__(256) void gates_gemm(
    const float* __restrict__ x,
    const float* __restrict__ Wf, const float* __restrict__ Wb,
    const float* __restrict__ bf, const float* __restrict__ bb,
    float* __restrict__ G, int Tc, int base)
{
    __shared__ __align__(16) float As[16][68];  // [k][m], +pad
    __shared__ __align__(16) float Bs[16][68];  // [k][n]
    const int tid   = threadIdx.x;
    const int mtile = blockIdx.x;   // 16 tiles over gate rows
    const int sl    = blockIdx.y;   // chunk-local step -> one t per block
    const int dir   = blockIdx.z;

    const float* W    = dir ? Wb : Wf;
    const float* bias = dir ? bb : bf;
    const int s = base + sl;
    const int t = dir ? (Tz - 1 - s) : s;

    const int lr = tid >> 2;         // 0..63 (row within tile)
    const int lk = (tid & 3) * 4;    // 0,4,8,12 (k offset)
    const float* Arow = W + (size_t)(mtile * 64 + lr) * Dz;
    const float* Brow = x + ((size_t)lr * Tz + t) * Dz;   // b = lr

    const int mg = tid >> 4;   // 0..15
    const int ng = tid & 15;   // 0..15
    float acc[4][4] = {};

    for (int kt = 0; kt < Dz; kt += 16) {
        float4 a4 = *(const float4*)(Arow + kt + lk);
        float4 b4 = *(const float4*)(Brow + kt + lk);
        __syncthreads();  // previous compute done reading tiles
        As[lk + 0][lr] = a4.x; As[lk + 1][lr] = a4.y;
        As[lk + 2][lr] = a4.z; As[lk + 3][lr] = a4.w;
        Bs[lk + 0][lr] = b4.x; Bs[lk + 1][lr] = b4.y;
        Bs[lk + 2][lr] = b4.z; Bs[lk + 3][lr] = b4.w;
        __syncthreads();
#pragma unroll
        for (int kk = 0; kk < 16; ++kk) {
            float4 av = *(const float4*)&As[kk][mg * 4];
            float4 bv = *(const float4*)&Bs[kk][ng * 4];
            acc[0][0] = fmaf(av.x, bv.x, acc[0][0]);
            acc[0][1] = fmaf(av.x, bv.y, acc[0][1]);
            acc[0][2] = fmaf(av.x, bv.z, acc[0][2]);
            acc[0][3] = fmaf(av.x, bv.w, acc[0][3]);
            acc[1][0] = fmaf(av.y, bv.x, acc[1][0]);
            acc[1][1] = fmaf(av.y, bv.y, acc[1][1]);
            acc[1][2] = fmaf(av.y, bv.z, acc[1][2]);
            acc[1][3] = fmaf(av.y, bv.w, acc[1][3]);
            acc[2][0] = fmaf(av.z, bv.x, acc[2][0]);
            acc[2][1] = fmaf(av.z, bv.y, acc[2][1]);
            acc[2][2] = fmaf(av.z, bv.z, acc[2][2]);
            acc[2][3] = fmaf(av.z, bv.w, acc[2][3]);
            acc[3][0] = fmaf(av.w, bv.x, acc[3][0]);
            acc[3][1] = fmaf(av.w, bv.y, acc[3][1]);
            acc[3][2] = fmaf(av.w, bv.z, acc[3][2]);
            acc[3][3] = fmaf(av.w, bv.w, acc[3][3]);
        }
    }
#pragma unroll
    for (int i = 0; i < 4; ++i) {
        int row = mtile * 64 + mg * 4 + i;
        float bvs = bias[row];
        float4 o;
        o.x = acc[i][0] + bvs; o.y = acc[i][1] + bvs;
        o.z = acc[i][2] + bvs; o.w = acc[i][3] + bvs;
        *(float4*)(G + (((size_t)dir * Gz + row) * Tc + sl) * 64 + ng * 4) = o;
    }
}

// ---------------------------------------------------------------------------
// Persistent recurrent kernel. 256 blocks: dir = blk&1, gb = blk>>1 (0..127).
// Block owns h-indices {2gb, 2gb+1} x all 64 batches. h double-buffered in ws
// ([parity][dir][k][b]); per-step device-scope flag barrier per direction.
// c-state lives in registers of tid<128, persisted to ws across chunk launches.
// ---------------------------------------------------------------------------
__global__ __launch_bounds__(256) void lstm_rec(
    const float* __restrict__ G,      // [2][1024][Tc][64]
    const float* __restrict__ Whf, const float* __restrict__ Whb,
    float* __restrict__ hbuf,         // [2 parity][2 dir][256][64]
    float* __restrict__ cbuf,         // [2 dir][256][64]
    float* __restrict__ out1,         // lstm_o [64][1024][512] (d_out slot 1)
    int* flags, int Tc, int base)
{
    __shared__ __align__(16) float h_l[Hz][64];   // 64 KB, [k][b] conflict-free
    __shared__ float W_l[8][Hz];                  // 8 KB: block's W_hh rows
    __shared__ float gl[8][64];                   // staged gate values

    const int tid = threadIdx.x;
    const int dir = blockIdx.x & 1;
    const int gb  = blockIdx.x >> 1;  // 0..127
    const float* Whh = dir ? Whb : Whf;

    // Load W_hh rows: lr = q*2+j  ->  global row q*256 + 2gb + j
    for (int i = tid; i < 8 * Hz; i += 256) {
        int lr2 = i >> 8, kk = i & 255;
        int q = lr2 >> 1, j = lr2 & 1;
        W_l[lr2][kk] = Whh[(size_t)(q * Hz + gb * 2 + j) * Hz + kk];
    }

    const int b  = tid & 63;
    const int rq = tid >> 6;          // gate index 0..3 (i,f,g,o)
    const int jj = tid >> 6;          // for tid<128: h-index offset 0/1
    float c_reg = 0.0f;
    if (tid < 128) c_reg = cbuf[((size_t)dir * Hz + gb * 2 + jj) * 64 + b];
    __syncthreads();

    for (int sl = 0; sl < Tc; ++sl) {
        const int s = base + sl;
        if (s > 0) {
            if (tid == 0) {
                int* fp = flags + dir * Tz + (s - 1);
                while (__hip_atomic_load(fp, __ATOMIC_RELAXED, __HIP_MEMORY_SCOPE_AGENT) < 128)
                    __builtin_amdgcn_s_sleep(8);
            }
            __syncthreads();
            __threadfence();  // acquire: invalidate L1 so staged h is fresh
        }
        // stage h_s (parity s&1) into LDS
        const float* hsrc = hbuf + (size_t)(((s & 1) * 2 + dir) * Hz) * 64;
        for (int i = tid * 4; i < Hz * 64; i += 1024)
            *(float4*)((float*)h_l + i) = *(const float4*)(hsrc + i);
        __syncthreads();

        const int row0 = rq * Hz + gb * 2;
        float acc0 = G[(((size_t)dir * Gz + row0)     * Tc + sl) * 64 + b];
        float acc1 = G[(((size_t)dir * Gz + row0 + 1) * Tc + sl) * 64 + b];
        const float* w0 = W_l[rq * 2];
        const float* w1 = W_l[rq * 2 + 1];
#pragma unroll 8
        for (int k = 0; k < Hz; ++k) {
            float hv = h_l[k][b];
            acc0 = fmaf(hv, w0[k], acc0);
            acc1 = fmaf(hv, w1[k], acc1);
        }
        gl[rq * 2][b]     = acc0;
        gl[rq * 2 + 1][b] = acc1;
        __syncthreads();

        if (tid < 128) {
            float gi = sigf(gl[0 + jj][b]);
            float gf = sigf(gl[2 + jj][b]);
            float gg = tanhf(gl[4 + jj][b]);
            float go = sigf(gl[6 + jj][b]);
            c_reg = gf * c_reg + gi * gg;
            float hv = go * tanhf(c_reg);
            int hx = gb * 2 + jj;
            hbuf[((size_t)(((s + 1) & 1) * 2 + dir) * Hz + hx) * 64 + b] = hv;
            int tt  = dir ? (Tz - 1 - s) : s;
            int col = dir ? (Hz + hx) : hx;
            out1[((size_t)b * Tz + tt) * Dz + col] = hv;   // scattered; fix later
        }
        __threadfence();   // release h stores before arrival
        __syncthreads();
        if (tid == 0) atomicAdd(flags + dir * Tz + s, 1);
    }
    if (tid < 128) cbuf[((size_t)dir * Hz + gb * 2 + jj) * 64 + b] = c_reg;
}

// ---------------------------------------------------------------------------
// Head: logits -> 20 smallest (ascending value, lower-index ties; softmax is
// monotone so smallest probs == smallest logits) -> indices + sgn_mask.
// One block per batch.
// ---------------------------------------------------------------------------
__global__ __launch_bounds__(256) void head_kernel(
    const float* __restrict__ out1, const float* __restrict__ lin_w,
    const float* __restrict__ lin_b, const unsigned char* __restrict__ mask8,
    float* __restrict__ out0, float* __restrict__ out2)
{
    __shared__ __align__(16) float lw[Dz];
    __shared__ float llog[Tz];
    __shared__ unsigned char hit[Tz];
    __shared__ float redv[4];
    __shared__ int   redi[4];

    const int tid = threadIdx.x;
    const int bb  = blockIdx.x;
    for (int i = tid; i < Dz; i += 256) lw[i] = lin_w[i];
    for (int i = tid; i < Tz; i += 256) hit[i] = 0;
    __syncthreads();

    const int w = tid >> 6, lane = tid & 63;
    const float lbv = lin_b[0];
    for (int t = w; t < Tz; t += 4) {   // one wave per t
        const float* rp = out1 + ((size_t)bb * Tz + t) * Dz + lane * 8;
        float4 a0 = *(const float4*)rp;
        float4 a1 = *(const float4*)(rp + 4);
        const float* wp = lw + lane * 8;
        float ps = a0.x * wp[0] + a0.y * wp[1] + a0.z * wp[2] + a0.w * wp[3]
                 + a1.x * wp[4] + a1.y * wp[5] + a1.z * wp[6] + a1.w * wp[7];
        for (int o = 32; o; o >>= 1) ps += __shfl_down(ps, o);
        if (lane == 0) llog[t] = ps + lbv;
    }
    __syncthreads();

    for (int it = 0; it < Kz; ++it) {
        float bv = 3.4e38f; int bi = Tz;
        for (int t = tid; t < Tz; t += 256) {   // ascending t: strict < keeps low idx
            float v = llog[t];
            if (v < bv) { bv = v; bi = t; }
        }
        for (int o = 32; o; o >>= 1) {
            float ov = __shfl_down(bv, o);
            int   oi = __shfl_down(bi, o);
            if (ov < bv || (ov == bv && oi < bi)) { bv = ov; bi = oi; }
        }
        if (lane == 0) { redv[w] = bv; redi[w] = bi; }
        __syncthreads();
        if (tid == 0) {
            for (int q = 1; q < 4; ++q)
                if (redv[q] < bv || (redv[q] == bv && redi[q] < bi)) { bv = redv[q]; bi = redi[q]; }
            out0[bb * Kz + it] = (float)bi;   // indices as float (buffer is f32)
            llog[bi] = 3.4e38f;
            hit[bi] = 1;
        }
        __syncthreads();
    }
    // sgn_mask = mask & ~hit, as 0.0/1.0. mask is numpy bool -> 1 byte/elem.
    for (int t = tid; t < Tz; t += 256) {
        bool mv = mask8[(size_t)bb * Tz + t] != 0;
        out2[(size_t)bb * Tz + t] = (mv && !hit[t]) ? 1.0f : 0.0f;
    }
}

// ---------------------------------------------------------------------------
// In-place LayerNorm over last dim (512), eps=1e-5. One wave per row.
// ---------------------------------------------------------------------------
__global__ __launch_bounds__(256) void ln_kernel(
    float* __restrict__ out1, const float* __restrict__ ln_g,
    const float* __restrict__ ln_b)
{
    const int tid = threadIdx.x;
    const int w = tid >> 6, lane = tid & 63;
    const size_t row = (size_t)blockIdx.x * 4 + w;
    float* rp = out1 + row * Dz + lane * 8;
    float4 a0 = *(float4*)rp;
    float4 a1 = *(float4*)(rp + 4);
    float s  = a0.x + a0.y + a0.z + a0.w + a1.x + a1.y + a1.z + a1.w;
    float sq = a0.x*a0.x + a0.y*a0.y + a0.z*a0.z + a0.w*a0.w
             + a1.x*a1.x + a1.y*a1.y + a1.z*a1.z + a1.w*a1.w;
    for (int o = 32; o; o >>= 1) { s += __shfl_down(s, o); sq += __shfl_down(sq, o); }
    s  = __shfl(s, 0);
    sq = __shfl(sq, 0);
    const float mu  = s * (1.0f / Dz);
    const float var = sq * (1.0f / Dz) - mu * mu;
    const float rs  = rsqrtf(var + 1e-5f);
    const float* gp = ln_g + lane * 8;
    const float* bp = ln_b + lane * 8;
    a0.x = (a0.x - mu) * rs * gp[0] + bp[0];
    a0.y = (a0.y - mu) * rs * gp[1] + bp[1];
    a0.z = (a0.z - mu) * rs * gp[2] + bp[2];
    a0.w = (a0.w - mu) * rs * gp[3] + bp[3];
    a1.x = (a1.x - mu) * rs * gp[4] + bp[4];
    a1.y = (a1.y - mu) * rs * gp[5] + bp[5];
    a1.z = (a1.z - mu) * rs * gp[6] + bp[6];
    a1.w = (a1.w - mu) * rs * gp[7] + bp[7];
    *(float4*)rp = a0;
    *(float4*)(rp + 4) = a1;
}

// ---------------------------------------------------------------------------
extern "C" void kernel_launch(void* const* d_in, const int* in_sizes, int n_in,
                              void* d_out, int out_size, void* d_ws, size_t ws_size,
                              hipStream_t stream)
{
    (void)in_sizes; (void)n_in; (void)out_size;
    const float* x     = (const float*)d_in[0];
    const float* Wif   = (const float*)d_in[1];
    const float* Whf   = (const float*)d_in[2];
    const float* bf    = (const float*)d_in[3];
    const float* Wib   = (const float*)d_in[4];
    const float* Whb   = (const float*)d_in[5];
    const float* bb    = (const float*)d_in[6];
    const float* lin_w = (const float*)d_in[7];
    const float* lin_b = (const float*)d_in[8];
    const float* ln_g  = (const float*)d_in[9];
    const float* ln_b  = (const float*)d_in[10];
    const unsigned char* mask8 = (const unsigned char*)d_in[11];
    // d_in[12] = input_len (1024), d_in[13] = k (20): fixed, hardcoded.

    float* ws    = (float*)d_ws;
    int*   flags = (int*)d_ws;                      // 2048 ints
    float* hbuf  = ws + 2048;                       // 65536 floats
    float* cbuf  = ws + 2048 + 65536;               // 32768 floats
    float* gates = ws + 2048 + 65536 + 32768;       // chunked gates

    const size_t fixedBytes = (size_t)(2048 + 65536 + 32768) * 4;  // 401408
    const size_t avail = ws_size > fixedBytes ? ws_size - fixedBytes : 0;
    int Tc = 8;
    for (int cand = 256; cand >= 8; cand >>= 1) {
        if ((size_t)cand * (2ull * Gz * 64 * 4) <= avail) { Tc = cand; break; }
    }

    float* out0 = (float*)d_out;
    float* out1 = out0 + (size_t)Bz * Kz;           // 1280
    float* out2 = out1 + (size_t)Bz * Tz * Dz;

    init_ws<<<dim3((100352 + 255) / 256), 256, 0, stream>>>((int*)d_ws);

    const int nChunks = Tz / Tc;
    for (int c = 0; c < nChunks; ++c) {
        const int base = c * Tc;
        gates_gemm<<<dim3(16, Tc, 2), 256, 0, stream>>>(x, Wif, Wib, bf, bb, gates, Tc, base);
        lstm_rec<<<dim3(256), 256, 0, stream>>>(gates, Whf, Whb, hbuf, cbuf, out1, flags, Tc, base);
    }
    head_kernel<<<dim3(Bz), 256, 0, stream>>>(out1, lin_w, lin_b, mask8, out0, out2);
    ln_kernel<<<dim3((Bz * Tz) / 4), 256, 0, stream>>>(out1, ln_g, ln_b);
}

// Round 2
// 15102.464 us; speedup vs baseline: 3.7374x; 3.7374x over previous
//
#include <hip/hip_runtime.h>
#include <math.h>

// Problem constants (fixed by setup_inputs)
#define Bz 64
#define Tz 1024
#define Dz 512
#define Hz 256
#define Gz 1024   // 4*H
#define Kz 20

__device__ __forceinline__ float sigf(float x) { return 1.0f / (1.0f + __expf(-x)); }

// ---------------------------------------------------------------------------
// Zero-init persistent ws region: flags (2048 ints) + hbuf (65536 f) + cbuf
// (32768 f) = 100352 dwords.
// ---------------------------------------------------------------------------
__global__ __launch_bounds__(256) void init_ws(int* p) {
    int i = blockIdx.x * 256 + threadIdx.x;
    if (i < 100352) p[i] = 0;
}

// ---------------------------------------------------------------------------
// Input-gate precompute GEMM (fp32, LDS-tiled 64x64, 4x4 microtile).
// G[dir][row][sl][b] = bias[row] + sum_k W_ih[row][k] * x[b][t(dir,sl)][k]
// ---------------------------------------------------------------------------
__global__ __launch_bounds__(256) void gates_gemm(
    const float* __restrict__ x,
    const float* __restrict__ Wf, const float* __restrict__ Wb,
    const float* __restrict__ bf, const float* __restrict__ bb,
    float* __restrict__ G, int Tc, int base)
{
    __shared__ __align__(16) float As[16][68];  // [k][m], +pad
    __shared__ __align__(16) float Bs[16][68];  // [k][n]
    const int tid   = threadIdx.x;
    const int mtile = blockIdx.x;   // 16 tiles over gate rows
    const int sl    = blockIdx.y;   // chunk-local step
    const int dir   = blockIdx.z;

    const float* W    = dir ? Wb : Wf;
    const float* bias = dir ? bb : bf;
    const int s = base + sl;
    const int t = dir ? (Tz - 1 - s) : s;

    const int lr = tid >> 2;         // 0..63
    const int lk = (tid & 3) * 4;    // 0,4,8,12
    const float* Arow = W + (size_t)(mtile * 64 + lr) * Dz;
    const float* Brow = x + ((size_t)lr * Tz + t) * Dz;   // b = lr

    const int mg = tid >> 4;   // 0..15
    const int ng = tid & 15;   // 0..15
    float acc[4][4] = {};

    for (int kt = 0; kt < Dz; kt += 16) {
        float4 a4 = *(const float4*)(Arow + kt + lk);
        float4 b4 = *(const float4*)(Brow + kt + lk);
        __syncthreads();
        As[lk + 0][lr] = a4.x; As[lk + 1][lr] = a4.y;
        As[lk + 2][lr] = a4.z; As[lk + 3][lr] = a4.w;
        Bs[lk + 0][lr] = b4.x; Bs[lk + 1][lr] = b4.y;
        Bs[lk + 2][lr] = b4.z; Bs[lk + 3][lr] = b4.w;
        __syncthreads();
#pragma unroll
        for (int kk = 0; kk < 16; ++kk) {
            float4 av = *(const float4*)&As[kk][mg * 4];
            float4 bv = *(const float4*)&Bs[kk][ng * 4];
            acc[0][0] = fmaf(av.x, bv.x, acc[0][0]);
            acc[0][1] = fmaf(av.x, bv.y, acc[0][1]);
            acc[0][2] = fmaf(av.x, bv.z, acc[0][2]);
            acc[0][3] = fmaf(av.x, bv.w, acc[0][3]);
            acc[1][0] = fmaf(av.y, bv.x, acc[1][0]);
            acc[1][1] = fmaf(av.y, bv.y, acc[1][1]);
            acc[1][2] = fmaf(av.y, bv.z, acc[1][2]);
            acc[1][3] = fmaf(av.y, bv.w, acc[1][3]);
            acc[2][0] = fmaf(av.z, bv.x, acc[2][0]);
            acc[2][1] = fmaf(av.z, bv.y, acc[2][1]);
            acc[2][2] = fmaf(av.z, bv.z, acc[2][2]);
            acc[2][3] = fmaf(av.z, bv.w, acc[2][3]);
            acc[3][0] = fmaf(av.w, bv.x, acc[3][0]);
            acc[3][1] = fmaf(av.w, bv.y, acc[3][1]);
            acc[3][2] = fmaf(av.w, bv.z, acc[3][2]);
            acc[3][3] = fmaf(av.w, bv.w, acc[3][3]);
        }
    }
#pragma unroll
    for (int i = 0; i < 4; ++i) {
        int row = mtile * 64 + mg * 4 + i;
        float bvs = bias[row];
        float4 o;
        o.x = acc[i][0] + bvs; o.y = acc[i][1] + bvs;
        o.z = acc[i][2] + bvs; o.w = acc[i][3] + bvs;
        *(float4*)(G + (((size_t)dir * Gz + row) * Tc + sl) * 64 + ng * 4) = o;
    }
}

// ---------------------------------------------------------------------------
// Persistent recurrent kernel v2 — NO data fences. 128 blocks = 2 dirs x 64
// h-groups; block owns h-indices {4g..4g+3} (16 gate rows) x all 64 batches.
// h exchanged via AGENT-scope relaxed atomic load/store (coherent MUBUF sc
// bits: no L2 writeback storms), ordered by s_waitcnt vmcnt(0) + one flag
// atomicAdd per block per step. 84 KB LDS -> 1 block/CU, 128 <= 256 CUs, all
// co-resident => spin barrier cannot deadlock.
// ---------------------------------------------------------------------------
__global__ __launch_bounds__(256, 1) void lstm_rec(
    const float* __restrict__ G,      // [2][1024][Tc][64]
    const float* __restrict__ Whf, const float* __restrict__ Whb,
    float* __restrict__ hbuf,         // [2 parity][2 dir][256][64]
    float* __restrict__ cbuf,         // [2 dir][256][64]
    float* __restrict__ out1,         // lstm_o [64][1024][512]
    int* flags, int Tc, int base)
{
    __shared__ __align__(16) float h_l[Hz * 64];   // 64 KB  [k][b]
    __shared__ __align__(16) float W_l[16][Hz];    // 16 KB  [(q,j)][k]
    __shared__ float gl[16][64];                   // 4 KB   staged gate values

    const int tid = threadIdx.x;
    const int dir = blockIdx.x >> 6;   // 0..1
    const int g   = blockIdx.x & 63;   // h-group
    const float* Whh = dir ? Whb : Whf;

    // Load the block's 16 W_hh rows: local (q,j) -> global row q*Hz + 4g + j
    for (int f = tid; f < 16 * Hz; f += 256) {
        int lr = f >> 8, k = f & 255;
        int q = lr >> 2, j = lr & 3;
        W_l[lr][k] = Whh[(size_t)(q * Hz + g * 4 + j) * Hz + k];
    }

    const int b  = tid & 63;
    const int q  = tid >> 6;   // gate index for matvec phase
    const int j_ = tid >> 6;   // h-offset for activation phase
    float c_reg = cbuf[((size_t)dir * Hz + g * 4 + j_) * 64 + b];
    __syncthreads();

    const float* w0 = &W_l[q * 4 + 0][0];
    const float* w1 = &W_l[q * 4 + 1][0];
    const float* w2 = &W_l[q * 4 + 2][0];
    const float* w3 = &W_l[q * 4 + 3][0];

    for (int sl = 0; sl < Tc; ++sl) {
        const int s = base + sl;

        // prefetch this step's input-gate contributions (independent of h)
        float acc[4];
#pragma unroll
        for (int j = 0; j < 4; ++j)
            acc[j] = G[(((size_t)dir * Gz + q * Hz + g * 4 + j) * Tc + sl) * 64 + b];

        if (s > 0) {
            if (tid == 0) {
                int* fp = flags + dir * Tz + (s - 1);
                while (__hip_atomic_load(fp, __ATOMIC_RELAXED, __HIP_MEMORY_SCOPE_AGENT) < 64)
                    __builtin_amdgcn_s_sleep(1);
            }
            __syncthreads();
        }

        // stage h_s (parity s&1) into LDS via coherent 8B loads (coalesced)
        const unsigned long long* hsrc = (const unsigned long long*)
            (hbuf + (size_t)((s & 1) * 2 + dir) * Hz * 64);
        unsigned long long tmp[32];
#pragma unroll
        for (int jj = 0; jj < 32; ++jj)
            tmp[jj] = __hip_atomic_load(hsrc + jj * 256 + tid,
                                        __ATOMIC_RELAXED, __HIP_MEMORY_SCOPE_AGENT);
#pragma unroll
        for (int jj = 0; jj < 32; ++jj)
            ((unsigned long long*)h_l)[jj * 256 + tid] = tmp[jj];
        __syncthreads();

        // matvec: 4 rows x 256 k. W reads are wave-uniform (LDS broadcast
        // b128); h reads are lane=b conflict-free b32.
#pragma unroll 8
        for (int k = 0; k < Hz; k += 4) {
            const float4 wa = *(const float4*)(w0 + k);
            const float4 wb4 = *(const float4*)(w1 + k);
            const float4 wc = *(const float4*)(w2 + k);
            const float4 wd = *(const float4*)(w3 + k);
            const float h0 = h_l[(k + 0) * 64 + b];
            const float h1 = h_l[(k + 1) * 64 + b];
            const float h2 = h_l[(k + 2) * 64 + b];
            const float h3 = h_l[(k + 3) * 64 + b];
            acc[0] = fmaf(h0, wa.x, acc[0]);
            acc[0] = fmaf(h1, wa.y, acc[0]);
            acc[0] = fmaf(h2, wa.z, acc[0]);
            acc[0] = fmaf(h3, wa.w, acc[0]);
            acc[1] = fmaf(h0, wb4.x, acc[1]);
            acc[1] = fmaf(h1, wb4.y, acc[1]);
            acc[1] = fmaf(h2, wb4.z, acc[1]);
            acc[1] = fmaf(h3, wb4.w, acc[1]);
            acc[2] = fmaf(h0, wc.x, acc[2]);
            acc[2] = fmaf(h1, wc.y, acc[2]);
            acc[2] = fmaf(h2, wc.z, acc[2]);
            acc[2] = fmaf(h3, wc.w, acc[2]);
            acc[3] = fmaf(h0, wd.x, acc[3]);
            acc[3] = fmaf(h1, wd.y, acc[3]);
            acc[3] = fmaf(h2, wd.z, acc[3]);
            acc[3] = fmaf(h3, wd.w, acc[3]);
        }
#pragma unroll
        for (int j = 0; j < 4; ++j) gl[q * 4 + j][b] = acc[j];
        __syncthreads();

        // activations: thread (j_, b) owns h-index hx = 4g + j_
        {
            float gi = sigf(gl[j_][b]);
            float gf = sigf(gl[4 + j_][b]);
            float gg = tanhf(gl[8 + j_][b]);
            float go = sigf(gl[12 + j_][b]);
            c_reg = gf * c_reg + gi * gg;
            float hv = go * tanhf(c_reg);
            const int hx = g * 4 + j_;
            __hip_atomic_store(
                hbuf + ((size_t)(((s + 1) & 1) * 2 + dir) * Hz + hx) * 64 + b, hv,
                __ATOMIC_RELAXED, __HIP_MEMORY_SCOPE_AGENT);
            const int tt = dir ? (Tz - 1 - s) : s;
            out1[((size_t)b * Tz + tt) * Dz + dir * Hz + hx] = hv;
        }
        // drain stores, then signal. No cache-flushing fence needed: the h
        // stores are themselves device-coherent.
        asm volatile("s_waitcnt vmcnt(0)" ::: "memory");
        __syncthreads();
        if (tid == 0) atomicAdd(flags + dir * Tz + s, 1);
    }
    cbuf[((size_t)dir * Hz + g * 4 + j_) * 64 + b] = c_reg;
}

// ---------------------------------------------------------------------------
// Head: logits -> 20 smallest (softmax is monotone) -> indices + sgn_mask.
// ---------------------------------------------------------------------------
__global__ __launch_bounds__(256) void head_kernel(
    const float* __restrict__ out1, const float* __restrict__ lin_w,
    const float* __restrict__ lin_b, const unsigned char* __restrict__ mask8,
    float* __restrict__ out0, float* __restrict__ out2)
{
    __shared__ __align__(16) float lw[Dz];
    __shared__ float llog[Tz];
    __shared__ unsigned char hit[Tz];
    __shared__ float redv[4];
    __shared__ int   redi[4];

    const int tid = threadIdx.x;
    const int bb  = blockIdx.x;
    for (int i = tid; i < Dz; i += 256) lw[i] = lin_w[i];
    for (int i = tid; i < Tz; i += 256) hit[i] = 0;
    __syncthreads();

    const int w = tid >> 6, lane = tid & 63;
    const float lbv = lin_b[0];
    for (int t = w; t < Tz; t += 4) {
        const float* rp = out1 + ((size_t)bb * Tz + t) * Dz + lane * 8;
        float4 a0 = *(const float4*)rp;
        float4 a1 = *(const float4*)(rp + 4);
        const float* wp = lw + lane * 8;
        float ps = a0.x * wp[0] + a0.y * wp[1] + a0.z * wp[2] + a0.w * wp[3]
                 + a1.x * wp[4] + a1.y * wp[5] + a1.z * wp[6] + a1.w * wp[7];
        for (int o = 32; o; o >>= 1) ps += __shfl_down(ps, o);
        if (lane == 0) llog[t] = ps + lbv;
    }
    __syncthreads();

    for (int it = 0; it < Kz; ++it) {
        float bv = 3.4e38f; int bi = Tz;
        for (int t = tid; t < Tz; t += 256) {
            float v = llog[t];
            if (v < bv) { bv = v; bi = t; }
        }
        for (int o = 32; o; o >>= 1) {
            float ov = __shfl_down(bv, o);
            int   oi = __shfl_down(bi, o);
            if (ov < bv || (ov == bv && oi < bi)) { bv = ov; bi = oi; }
        }
        if (lane == 0) { redv[w] = bv; redi[w] = bi; }
        __syncthreads();
        if (tid == 0) {
            for (int qq = 1; qq < 4; ++qq)
                if (redv[qq] < bv || (redv[qq] == bv && redi[qq] < bi)) { bv = redv[qq]; bi = redi[qq]; }
            out0[bb * Kz + it] = (float)bi;
            llog[bi] = 3.4e38f;
            hit[bi] = 1;
        }
        __syncthreads();
    }
    for (int t = tid; t < Tz; t += 256) {
        bool mv = mask8[(size_t)bb * Tz + t] != 0;
        out2[(size_t)bb * Tz + t] = (mv && !hit[t]) ? 1.0f : 0.0f;
    }
}

// ---------------------------------------------------------------------------
// In-place LayerNorm over last dim (512), eps=1e-5. One wave per row.
// ---------------------------------------------------------------------------
__global__ __launch_bounds__(256) void ln_kernel(
    float* __restrict__ out1, const float* __restrict__ ln_g,
    const float* __restrict__ ln_b)
{
    const int tid = threadIdx.x;
    const int w = tid >> 6, lane = tid & 63;
    const size_t row = (size_t)blockIdx.x * 4 + w;
    float* rp = out1 + row * Dz + lane * 8;
    float4 a0 = *(float4*)rp;
    float4 a1 = *(float4*)(rp + 4);
    float s  = a0.x + a0.y + a0.z + a0.w + a1.x + a1.y + a1.z + a1.w;
    float sq = a0.x*a0.x + a0.y*a0.y + a0.z*a0.z + a0.w*a0.w
             + a1.x*a1.x + a1.y*a1.y + a1.z*a1.z + a1.w*a1.w;
    for (int o = 32; o; o >>= 1) { s += __shfl_down(s, o); sq += __shfl_down(sq, o); }
    s  = __shfl(s, 0);
    sq = __shfl(sq, 0);
    const float mu  = s * (1.0f / Dz);
    const float var = sq * (1.0f / Dz) - mu * mu;
    const float rs  = rsqrtf(var + 1e-5f);
    const float* gp = ln_g + lane * 8;
    const float* bp = ln_b + lane * 8;
    a0.x = (a0.x - mu) * rs * gp[0] + bp[0];
    a0.y = (a0.y - mu) * rs * gp[1] + bp[1];
    a0.z = (a0.z - mu) * rs * gp[2] + bp[2];
    a0.w = (a0.w - mu) * rs * gp[3] + bp[3];
    a1.x = (a1.x - mu) * rs * gp[4] + bp[4];
    a1.y = (a1.y - mu) * rs * gp[5] + bp[5];
    a1.z = (a1.z - mu) * rs * gp[6] + bp[6];
    a1.w = (a1.w - mu) * rs * gp[7] + bp[7];
    *(float4*)rp = a0;
    *(float4*)(rp + 4) = a1;
}

// ---------------------------------------------------------------------------
extern "C" void kernel_launch(void* const* d_in, const int* in_sizes, int n_in,
                              void* d_out, int out_size, void* d_ws, size_t ws_size,
                              hipStream_t stream)
{
    (void)in_sizes; (void)n_in; (void)out_size;
    const float* x     = (const float*)d_in[0];
    const float* Wif   = (const float*)d_in[1];
    const float* Whf   = (const float*)d_in[2];
    const float* bf    = (const float*)d_in[3];
    const float* Wib   = (const float*)d_in[4];
    const float* Whb   = (const float*)d_in[5];
    const float* bb    = (const float*)d_in[6];
    const float* lin_w = (const float*)d_in[7];
    const float* lin_b = (const float*)d_in[8];
    const float* ln_g  = (const float*)d_in[9];
    const float* ln_b  = (const float*)d_in[10];
    const unsigned char* mask8 = (const unsigned char*)d_in[11];

    float* ws    = (float*)d_ws;
    int*   flags = (int*)d_ws;                      // 2048 ints
    float* hbuf  = ws + 2048;                       // 65536 floats
    float* cbuf  = ws + 2048 + 65536;               // 32768 floats
    float* gates = ws + 2048 + 65536 + 32768;       // chunked gates

    const size_t fixedBytes = (size_t)(2048 + 65536 + 32768) * 4;
    const size_t avail = ws_size > fixedBytes ? ws_size - fixedBytes : 0;
    int Tc = 8;
    for (int cand = 256; cand >= 8; cand >>= 1) {
        if ((size_t)cand * (2ull * Gz * 64 * 4) <= avail) { Tc = cand; break; }
    }

    float* out0 = (float*)d_out;
    float* out1 = out0 + (size_t)Bz * Kz;
    float* out2 = out1 + (size_t)Bz * Tz * Dz;

    init_ws<<<dim3((100352 + 255) / 256), 256, 0, stream>>>((int*)d_ws);

    const int nChunks = Tz / Tc;
    for (int c = 0; c < nChunks; ++c) {
        const int base = c * Tc;
        gates_gemm<<<dim3(16, Tc, 2), 256, 0, stream>>>(x, Wif, Wib, bf, bb, gates, Tc, base);
        lstm_rec<<<dim3(128), 256, 0, stream>>>(gates, Whf, Whb, hbuf, cbuf, out1, flags, Tc, base);
    }
    head_kernel<<<dim3(Bz), 256, 0, stream>>>(out1, lin_w, lin_b, mask8, out0, out2);
    ln_kernel<<<dim3((Bz * Tz) / 4), 256, 0, stream>>>(out1, ln_g, ln_b);
}

// Round 3
// 13164.517 us; speedup vs baseline: 4.2876x; 1.1472x over previous
//
#include <hip/hip_runtime.h>
#include <math.h>

// Problem constants (fixed by setup_inputs)
#define Bz 64
#define Tz 1024
#define Dz 512
#define Hz 256
#define Gz 1024   // 4*H
#define Kz 20

__device__ __forceinline__ float sigf(float x) { return 1.0f / (1.0f + __expf(-x)); }

// ---------------------------------------------------------------------------
// Zero-init persistent ws region: flags (2048 ints) + hbuf (65536 f) + cbuf
// (32768 f) = 100352 dwords.
// ---------------------------------------------------------------------------
__global__ __launch_bounds__(256) void init_ws(int* p) {
    int i = blockIdx.x * 256 + threadIdx.x;
    if (i < 100352) p[i] = 0;
}

// ---------------------------------------------------------------------------
// Input-gate precompute GEMM (fp32, LDS-tiled 64x64, 4x4 microtile).
// G[dir][row][sl][b] = bias[row] + sum_k W_ih[row][k] * x[b][t(dir,sl)][k]
// ---------------------------------------------------------------------------
__global__ __launch_bounds__(256) void gates_gemm(
    const float* __restrict__ x,
    const float* __restrict__ Wf, const float* __restrict__ Wb,
    const float* __restrict__ bf, const float* __restrict__ bb,
    float* __restrict__ G, int Tc, int base)
{
    __shared__ __align__(16) float As[16][68];  // [k][m], +pad
    __shared__ __align__(16) float Bs[16][68];  // [k][n]
    const int tid   = threadIdx.x;
    const int mtile = blockIdx.x;   // 16 tiles over gate rows
    const int sl    = blockIdx.y;   // chunk-local step
    const int dir   = blockIdx.z;

    const float* W    = dir ? Wb : Wf;
    const float* bias = dir ? bb : bf;
    const int s = base + sl;
    const int t = dir ? (Tz - 1 - s) : s;

    const int lr = tid >> 2;         // 0..63
    const int lk = (tid & 3) * 4;    // 0,4,8,12
    const float* Arow = W + (size_t)(mtile * 64 + lr) * Dz;
    const float* Brow = x + ((size_t)lr * Tz + t) * Dz;   // b = lr

    const int mg = tid >> 4;   // 0..15
    const int ng = tid & 15;   // 0..15
    float acc[4][4] = {};

    for (int kt = 0; kt < Dz; kt += 16) {
        float4 a4 = *(const float4*)(Arow + kt + lk);
        float4 b4 = *(const float4*)(Brow + kt + lk);
        __syncthreads();
        As[lk + 0][lr] = a4.x; As[lk + 1][lr] = a4.y;
        As[lk + 2][lr] = a4.z; As[lk + 3][lr] = a4.w;
        Bs[lk + 0][lr] = b4.x; Bs[lk + 1][lr] = b4.y;
        Bs[lk + 2][lr] = b4.z; Bs[lk + 3][lr] = b4.w;
        __syncthreads();
#pragma unroll
        for (int kk = 0; kk < 16; ++kk) {
            float4 av = *(const float4*)&As[kk][mg * 4];
            float4 bv = *(const float4*)&Bs[kk][ng * 4];
            acc[0][0] = fmaf(av.x, bv.x, acc[0][0]);
            acc[0][1] = fmaf(av.x, bv.y, acc[0][1]);
            acc[0][2] = fmaf(av.x, bv.z, acc[0][2]);
            acc[0][3] = fmaf(av.x, bv.w, acc[0][3]);
            acc[1][0] = fmaf(av.y, bv.x, acc[1][0]);
            acc[1][1] = fmaf(av.y, bv.y, acc[1][1]);
            acc[1][2] = fmaf(av.y, bv.z, acc[1][2]);
            acc[1][3] = fmaf(av.y, bv.w, acc[1][3]);
            acc[2][0] = fmaf(av.z, bv.x, acc[2][0]);
            acc[2][1] = fmaf(av.z, bv.y, acc[2][1]);
            acc[2][2] = fmaf(av.z, bv.z, acc[2][2]);
            acc[2][3] = fmaf(av.z, bv.w, acc[2][3]);
            acc[3][0] = fmaf(av.w, bv.x, acc[3][0]);
            acc[3][1] = fmaf(av.w, bv.y, acc[3][1]);
            acc[3][2] = fmaf(av.w, bv.z, acc[3][2]);
            acc[3][3] = fmaf(av.w, bv.w, acc[3][3]);
        }
    }
#pragma unroll
    for (int i = 0; i < 4; ++i) {
        int row = mtile * 64 + mg * 4 + i;
        float bvs = bias[row];
        float4 o;
        o.x = acc[i][0] + bvs; o.y = acc[i][1] + bvs;
        o.z = acc[i][2] + bvs; o.w = acc[i][3] + bvs;
        *(float4*)(G + (((size_t)dir * Gz + row) * Tc + sl) * 64 + ng * 4) = o;
    }
}

// ---------------------------------------------------------------------------
// Persistent recurrent kernel v3. 128 blocks = 2 dirs x 64 h-groups; block
// owns h-indices {4g..4g+3} (16 gate rows) x all 64 batches.
//
// Step barrier v3: NO atomicAdd counting (v2's 64 serialized RMWs on one
// line were ~12.9us/step). Producer block g stores a monotone step stamp to
// its OWN dword pflag[dir*64+g] (relaxed, agent scope); consumers poll all
// 64 flags with ONE coalesced 256B coherent load by wave 0 + __all().
// Ordering: h stores -> s_waitcnt vmcnt(0) -> syncthreads -> flag store, so
// a consumer that sees stamp >= s also sees h_s at the coherence point.
// Safe overwrite: stamp s+1 implies that block already STAGED h_s into its
// LDS, so parity buffer (s&1) may be overwritten by h_{s+2}.
// ---------------------------------------------------------------------------
__global__ __launch_bounds__(256, 1) void lstm_rec(
    const float* __restrict__ G,      // [2][1024][Tc][64]
    const float* __restrict__ Whf, const float* __restrict__ Whb,
    float* __restrict__ hbuf,         // [2 parity][2 dir][256][64]
    float* __restrict__ cbuf,         // [2 dir][256][64]
    float* __restrict__ out1,         // lstm_o [64][1024][512]
    int* pflag, int Tc, int base)
{
    __shared__ __align__(16) float h_l[Hz * 64];   // 64 KB  [k][b]
    __shared__ __align__(16) float W_l[16][Hz];    // 16 KB  [(q,j)][k]
    __shared__ float gl[16][64];                   // 4 KB   staged gate values

    const int tid = threadIdx.x;
    const int dir = blockIdx.x >> 6;   // 0..1
    const int g   = blockIdx.x & 63;   // h-group
    const float* Whh = dir ? Whb : Whf;

    // Load the block's 16 W_hh rows: local (q,j) -> global row q*Hz + 4g + j
    for (int f = tid; f < 16 * Hz; f += 256) {
        int lr = f >> 8, k = f & 255;
        int q = lr >> 2, j = lr & 3;
        W_l[lr][k] = Whh[(size_t)(q * Hz + g * 4 + j) * Hz + k];
    }

    const int b  = tid & 63;
    const int q  = tid >> 6;   // gate index for matvec phase
    const int j_ = tid >> 6;   // h-offset for activation phase
    float c_reg = cbuf[((size_t)dir * Hz + g * 4 + j_) * 64 + b];
    __syncthreads();

    const float* w0 = &W_l[q * 4 + 0][0];
    const float* w1 = &W_l[q * 4 + 1][0];
    const float* w2 = &W_l[q * 4 + 2][0];
    const float* w3 = &W_l[q * 4 + 3][0];

    for (int sl = 0; sl < Tc; ++sl) {
        const int s = base + sl;

        // prefetch this step's input-gate contributions (independent of h)
        float acc[4];
#pragma unroll
        for (int j = 0; j < 4; ++j)
            acc[j] = G[(((size_t)dir * Gz + q * Hz + g * 4 + j) * Tc + sl) * 64 + b];

        if (s > 0) {
            if (tid < 64) {
                const int* fp = pflag + dir * 64 + tid;
                for (;;) {
                    int v = __hip_atomic_load(fp, __ATOMIC_RELAXED,
                                              __HIP_MEMORY_SCOPE_AGENT);
                    if (__all(v >= s)) break;   // all producers done step s-1
                    __builtin_amdgcn_s_sleep(2);
                }
            }
            __syncthreads();
        }

        // stage h_s (parity s&1) into LDS via coherent 8B loads (coalesced)
        const unsigned long long* hsrc = (const unsigned long long*)
            (hbuf + (size_t)((s & 1) * 2 + dir) * Hz * 64);
        unsigned long long tmp[32];
#pragma unroll
        for (int jj = 0; jj < 32; ++jj)
            tmp[jj] = __hip_atomic_load(hsrc + jj * 256 + tid,
                                        __ATOMIC_RELAXED, __HIP_MEMORY_SCOPE_AGENT);
#pragma unroll
        for (int jj = 0; jj < 32; ++jj)
            ((unsigned long long*)h_l)[jj * 256 + tid] = tmp[jj];
        __syncthreads();

        // matvec: 4 rows x 256 k. W reads are wave-uniform LDS broadcast
        // b128; h reads are lane=b conflict-free b32.
#pragma unroll 8
        for (int k = 0; k < Hz; k += 4) {
            const float4 wa  = *(const float4*)(w0 + k);
            const float4 wb4 = *(const float4*)(w1 + k);
            const float4 wc  = *(const float4*)(w2 + k);
            const float4 wd  = *(const float4*)(w3 + k);
            const float h0 = h_l[(k + 0) * 64 + b];
            const float h1 = h_l[(k + 1) * 64 + b];
            const float h2 = h_l[(k + 2) * 64 + b];
            const float h3 = h_l[(k + 3) * 64 + b];
            acc[0] = fmaf(h0, wa.x, acc[0]);
            acc[0] = fmaf(h1, wa.y, acc[0]);
            acc[0] = fmaf(h2, wa.z, acc[0]);
            acc[0] = fmaf(h3, wa.w, acc[0]);
            acc[1] = fmaf(h0, wb4.x, acc[1]);
            acc[1] = fmaf(h1, wb4.y, acc[1]);
            acc[1] = fmaf(h2, wb4.z, acc[1]);
            acc[1] = fmaf(h3, wb4.w, acc[1]);
            acc[2] = fmaf(h0, wc.x, acc[2]);
            acc[2] = fmaf(h1, wc.y, acc[2]);
            acc[2] = fmaf(h2, wc.z, acc[2]);
            acc[2] = fmaf(h3, wc.w, acc[2]);
            acc[3] = fmaf(h0, wd.x, acc[3]);
            acc[3] = fmaf(h1, wd.y, acc[3]);
            acc[3] = fmaf(h2, wd.z, acc[3]);
            acc[3] = fmaf(h3, wd.w, acc[3]);
        }
#pragma unroll
        for (int j = 0; j < 4; ++j) gl[q * 4 + j][b] = acc[j];
        __syncthreads();

        // activations: thread (j_, b) owns h-index hx = 4g + j_
        float gi = sigf(gl[j_][b]);
        float gf = sigf(gl[4 + j_][b]);
        float gg = tanhf(gl[8 + j_][b]);
        float go = sigf(gl[12 + j_][b]);
        c_reg = gf * c_reg + gi * gg;
        const float hv = go * tanhf(c_reg);
        const int hx = g * 4 + j_;
        __hip_atomic_store(
            hbuf + ((size_t)(((s + 1) & 1) * 2 + dir) * Hz + hx) * 64 + b, hv,
            __ATOMIC_RELAXED, __HIP_MEMORY_SCOPE_AGENT);

        // drain the coherent h stores, then signal (single store, no RMW)
        asm volatile("s_waitcnt vmcnt(0)" ::: "memory");
        __syncthreads();
        if (tid == 0)
            __hip_atomic_store(pflag + dir * 64 + g, s + 1,
                               __ATOMIC_RELAXED, __HIP_MEMORY_SCOPE_AGENT);

        // non-critical output store AFTER the signal (off the critical path)
        const int tt = dir ? (Tz - 1 - s) : s;
        out1[((size_t)b * Tz + tt) * Dz + dir * Hz + hx] = hv;
    }
    cbuf[((size_t)dir * Hz + g * 4 + j_) * 64 + b] = c_reg;
}

// ---------------------------------------------------------------------------
// Head: logits -> 20 smallest (softmax is monotone) -> indices + sgn_mask.
// ---------------------------------------------------------------------------
__global__ __launch_bounds__(256) void head_kernel(
    const float* __restrict__ out1, const float* __restrict__ lin_w,
    const float* __restrict__ lin_b, const unsigned char* __restrict__ mask8,
    float* __restrict__ out0, float* __restrict__ out2)
{
    __shared__ __align__(16) float lw[Dz];
    __shared__ float llog[Tz];
    __shared__ unsigned char hit[Tz];
    __shared__ float redv[4];
    __shared__ int   redi[4];

    const int tid = threadIdx.x;
    const int bb  = blockIdx.x;
    for (int i = tid; i < Dz; i += 256) lw[i] = lin_w[i];
    for (int i = tid; i < Tz; i += 256) hit[i] = 0;
    __syncthreads();

    const int w = tid >> 6, lane = tid & 63;
    const float lbv = lin_b[0];
    for (int t = w; t < Tz; t += 4) {
        const float* rp = out1 + ((size_t)bb * Tz + t) * Dz + lane * 8;
        float4 a0 = *(const float4*)rp;
        float4 a1 = *(const float4*)(rp + 4);
        const float* wp = lw + lane * 8;
        float ps = a0.x * wp[0] + a0.y * wp[1] + a0.z * wp[2] + a0.w * wp[3]
                 + a1.x * wp[4] + a1.y * wp[5] + a1.z * wp[6] + a1.w * wp[7];
        for (int o = 32; o; o >>= 1) ps += __shfl_down(ps, o);
        if (lane == 0) llog[t] = ps + lbv;
    }
    __syncthreads();

    for (int it = 0; it < Kz; ++it) {
        float bv = 3.4e38f; int bi = Tz - 1;
        for (int t = tid; t < Tz; t += 256) {
            float v = llog[t];
            if (v < bv) { bv = v; bi = t; }
        }
        for (int o = 32; o; o >>= 1) {
            float ov = __shfl_down(bv, o);
            int   oi = __shfl_down(bi, o);
            if (ov < bv || (ov == bv && oi < bi)) { bv = ov; bi = oi; }
        }
        if (lane == 0) { redv[w] = bv; redi[w] = bi; }
        __syncthreads();
        if (tid == 0) {
            for (int qq = 1; qq < 4; ++qq)
                if (redv[qq] < bv || (redv[qq] == bv && redi[qq] < bi)) { bv = redv[qq]; bi = redi[qq]; }
            out0[bb * Kz + it] = (float)bi;
            llog[bi] = 3.4e38f;
            hit[bi] = 1;
        }
        __syncthreads();
    }
    for (int t = tid; t < Tz; t += 256) {
        bool mv = mask8[(size_t)bb * Tz + t] != 0;
        out2[(size_t)bb * Tz + t] = (mv && !hit[t]) ? 1.0f : 0.0f;
    }
}

// ---------------------------------------------------------------------------
// In-place LayerNorm over last dim (512), eps=1e-5. One wave per row.
// ---------------------------------------------------------------------------
__global__ __launch_bounds__(256) void ln_kernel(
    float* __restrict__ out1, const float* __restrict__ ln_g,
    const float* __restrict__ ln_b)
{
    const int tid = threadIdx.x;
    const int w = tid >> 6, lane = tid & 63;
    const size_t row = (size_t)blockIdx.x * 4 + w;
    float* rp = out1 + row * Dz + lane * 8;
    float4 a0 = *(float4*)rp;
    float4 a1 = *(float4*)(rp + 4);
    float s  = a0.x + a0.y + a0.z + a0.w + a1.x + a1.y + a1.z + a1.w;
    float sq = a0.x*a0.x + a0.y*a0.y + a0.z*a0.z + a0.w*a0.w
             + a1.x*a1.x + a1.y*a1.y + a1.z*a1.z + a1.w*a1.w;
    for (int o = 32; o; o >>= 1) { s += __shfl_down(s, o); sq += __shfl_down(sq, o); }
    s  = __shfl(s, 0);
    sq = __shfl(sq, 0);
    const float mu  = s * (1.0f / Dz);
    const float var = sq * (1.0f / Dz) - mu * mu;
    const float rs  = rsqrtf(var + 1e-5f);
    const float* gp = ln_g + lane * 8;
    const float* bp = ln_b + lane * 8;
    a0.x = (a0.x - mu) * rs * gp[0] + bp[0];
    a0.y = (a0.y - mu) * rs * gp[1] + bp[1];
    a0.z = (a0.z - mu) * rs * gp[2] + bp[2];
    a0.w = (a0.w - mu) * rs * gp[3] + bp[3];
    a1.x = (a1.x - mu) * rs * gp[4] + bp[4];
    a1.y = (a1.y - mu) * rs * gp[5] + bp[5];
    a1.z = (a1.z - mu) * rs * gp[6] + bp[6];
    a1.w = (a1.w - mu) * rs * gp[7] + bp[7];
    *(float4*)rp = a0;
    *(float4*)(rp + 4) = a1;
}

// ---------------------------------------------------------------------------
extern "C" void kernel_launch(void* const* d_in, const int* in_sizes, int n_in,
                              void* d_out, int out_size, void* d_ws, size_t ws_size,
                              hipStream_t stream)
{
    (void)in_sizes; (void)n_in; (void)out_size;
    const float* x     = (const float*)d_in[0];
    const float* Wif   = (const float*)d_in[1];
    const float* Whf   = (const float*)d_in[2];
    const float* bf    = (const float*)d_in[3];
    const float* Wib   = (const float*)d_in[4];
    const float* Whb   = (const float*)d_in[5];
    const float* bb    = (const float*)d_in[6];
    const float* lin_w = (const float*)d_in[7];
    const float* lin_b = (const float*)d_in[8];
    const float* ln_g  = (const float*)d_in[9];
    const float* ln_b  = (const float*)d_in[10];
    const unsigned char* mask8 = (const unsigned char*)d_in[11];

    float* ws    = (float*)d_ws;
    int*   flags = (int*)d_ws;                      // 2048 ints (128 used)
    float* hbuf  = ws + 2048;                       // 65536 floats
    float* cbuf  = ws + 2048 + 65536;               // 32768 floats
    float* gates = ws + 2048 + 65536 + 32768;       // chunked gates

    const size_t fixedBytes = (size_t)(2048 + 65536 + 32768) * 4;
    const size_t avail = ws_size > fixedBytes ? ws_size - fixedBytes : 0;
    int Tc = 8;
    for (int cand = 1024; cand >= 8; cand >>= 1) {
        if ((size_t)cand * (2ull * Gz * 64 * 4) <= avail) { Tc = cand; break; }
    }

    float* out0 = (float*)d_out;
    float* out1 = out0 + (size_t)Bz * Kz;
    float* out2 = out1 + (size_t)Bz * Tz * Dz;

    init_ws<<<dim3((100352 + 255) / 256), 256, 0, stream>>>((int*)d_ws);

    const int nChunks = Tz / Tc;
    for (int c = 0; c < nChunks; ++c) {
        const int base = c * Tc;
        gates_gemm<<<dim3(16, Tc, 2), 256, 0, stream>>>(x, Wif, Wib, bf, bb, gates, Tc, base);
        lstm_rec<<<dim3(128), 256, 0, stream>>>(gates, Whf, Whb, hbuf, cbuf, out1, flags, Tc, base);
    }
    head_kernel<<<dim3(Bz), 256, 0, stream>>>(out1, lin_w, lin_b, mask8, out0, out2);
    ln_kernel<<<dim3((Bz * Tz) / 4), 256, 0, stream>>>(out1, ln_g, ln_b);
}